// Round 5
// baseline (230.379 us; speedup 1.0000x reference)
//
#include <hip/hip_runtime.h>
#include <math.h>

#define EPSV 1e-4f
#define SCHUNK 64

typedef float f32x2 __attribute__((ext_vector_type(2)));  // clang-native: OK for nontemporal builtins

// Relaxed agent-scope atomics: point-wise LLC-coherent accesses (sc1), NO
// cache-wide invalidate/writeback (acquire/release would emit buffer_inv /
// buffer_wbl2 on gfx950 since per-XCD L2s are non-coherent -> catastrophic).
// Ordering is done manually with s_waitcnt vmcnt(0) before flag stores.
__device__ __forceinline__ float agent_load_f(const float* p) {
    return __hip_atomic_load(p, __ATOMIC_RELAXED, __HIP_MEMORY_SCOPE_AGENT);
}
__device__ __forceinline__ void agent_store_f(float* p, float v) {
    __hip_atomic_store(p, v, __ATOMIC_RELAXED, __HIP_MEMORY_SCOPE_AGENT);
}
__device__ __forceinline__ int agent_load_i(const int* p) {
    return __hip_atomic_load(p, __ATOMIC_RELAXED, __HIP_MEMORY_SCOPE_AGENT);
}
__device__ __forceinline__ void agent_store_i(int* p, int v) {
    __hip_atomic_store(p, v, __ATOMIC_RELAXED, __HIP_MEMORY_SCOPE_AGENT);
}

// ---------------- clear: all flags + ticket (one launch) ----------------
__global__ void clear_kernel(int* __restrict__ flags, int n) {
    int i = blockIdx.x * blockDim.x + threadIdx.x;
    if (i < n) flags[i] = 0;
}

// ---------------- fused b_flat scan -> sidx (single kernel) ----------------
// 256 blocks x 256 threads, 1024 b-elements per block.
// Block-level decoupled sum: publish block sum + flag; then thread i (< bid)
// spins on flags2[i] and loads bsum[i] IN PARALLEL, LDS tree-reduce -> offset.
// O(1) lookback depth, no serial chain. Deadlock-free: publish before wait.
__global__ __launch_bounds__(256) void sidx_kernel(
        const int* __restrict__ b, int n,
        int* __restrict__ bsum,
        int* __restrict__ flags2,
        int* __restrict__ sidx, int L, int Louter) {
    __shared__ int red[256];
    __shared__ int red2[256];
    const int tid = threadIdx.x;
    const int bid = blockIdx.x;
    const int base = bid * 1024 + tid * 4;

    int v[4];
    int s = 0;
#pragma unroll
    for (int k = 0; k < 4; ++k) {
        int j = base + k;
        v[k] = (j < n) ? b[j] : 0;
        s += v[k];
    }
    red[tid] = s;
    __syncthreads();
    // inclusive block scan (Hillis-Steele)
    for (int off = 1; off < 256; off <<= 1) {
        int t = red[tid];
        if (tid >= off) t += red[tid - off];
        __syncthreads();
        red[tid] = t;
        __syncthreads();
    }
    // publish block sum
    if (tid == 255) {
        agent_store_i(&bsum[bid], red[255]);
        asm volatile("s_waitcnt vmcnt(0)" ::: "memory");
        agent_store_i(&flags2[bid], 1);
    }
    // parallel lookback: thread i < bid grabs predecessor i's sum
    int mysum = 0;
    if (tid < bid) {
        while (agent_load_i(&flags2[tid]) == 0) __builtin_amdgcn_s_sleep(1);
        mysum = agent_load_i(&bsum[tid]);
    }
    red2[tid] = mysum;
    __syncthreads();
    for (int off = 128; off > 0; off >>= 1) {
        if (tid < off) red2[tid] += red2[tid + off];
        __syncthreads();
    }
    const int boff = red2[0];   // exclusive global prefix of this block

    // emit: sidx[t] = first out-row j of timestep t
    int cum = red[tid] - s + boff;
#pragma unroll
    for (int k = 0; k < 4; ++k) {
        int j = base + k;
        if (j < n) {
            cum += v[k];
            if (v[k] > 0) {
                int t = cum - 1;
                if (t >= 0 && t < L) sidx[t] = j;
            }
        }
    }
    if (tid == 0 && bid == 0) sidx[L] = Louter;
}

// ---------------- single-pass decoupled-lookback scan + scatter ----------------
// blockDim.x == d/2 (256): one thread owns 2 channels (f32x2, 8 B/lane).
// 4 waves/block x 2048 blocks = 32 waves/CU (full occupancy; round-4's 128-thread
// geometry halved TLP and regressed — latency hiding, not issue rate, binds).
// SCHUNK=64 timesteps per block. Pass 1: aggregate-only local scan (no z[]).
// Pass 2: re-read h (L2/LLC-hot) and rescan with carry folded in, scattering
// f32x2 directly to out. Thread 0 alone spins on predecessor flags.
// Deadlock-free: ticket => predecessors resident; flags published before wait.
__global__ __launch_bounds__(256, 8) void scan_lookback_kernel(
        const float* __restrict__ h,
        const float* __restrict__ psel,
        const int* __restrict__ seq,
        const int* __restrict__ sidx,
        float* __restrict__ out,
        float* __restrict__ aggE,   // [NC][d]
        float* __restrict__ aggP,   // [NC]
        int* __restrict__ flags,    // [NC] flags, flags[NC] = ticket
        int L, int d, int Louter, int NC) {
    __shared__ float sh_a[SCHUNK];
    __shared__ float sh_p[SCHUNK];
    __shared__ int   sh_j[SCHUNK + 1];
    __shared__ int   sh_g;
    __shared__ float sh_Pown;
    __shared__ float sh_Pbr;

    const int tid = threadIdx.x;
    if (tid == 0) sh_g = atomicAdd(&flags[NC], 1);  // device-scope ticket
    __syncthreads();
    const int g  = sh_g;
    const int t0 = g * SCHUNK;
    const int nt = min(SCHUNK, L - t0);

    // prologue: per-timestep scalars (fused prep) + scatter ranges into LDS
    if (tid < nt) {
        int t = t0 + tid;
        float p = psel[t];
        p = fminf(fmaxf(p, EPSV), 1.0f - EPSV);
        bool start = (t == 0) || (seq[t] != seq[t - 1]);
        sh_a[tid] = start ? 0.0f : (1.0f - p);   // exp(-dt) == 1-p exactly
        sh_p[tid] = p;                           // b_t = p*h
    }
    if (tid <= nt) sh_j[tid] = sidx[t0 + tid];   // sidx[L] sentinel exists
    __syncthreads();

    // chunk decay product P = prod(a) via wave-0 butterfly
    if (tid < 64) {
        float v = (tid < nt) ? sh_a[tid] : 1.0f;
#pragma unroll
        for (int m = 1; m < 64; m <<= 1) v *= __shfl_xor(v, m);
        if (tid == 0) sh_Pown = v;
    }

    const int c0 = tid * 2;
    const float* __restrict__ hp = h + (size_t)t0 * d + c0;

    // ---- pass 1: aggregate-only local scan (zero init) ----
    f32x2 st = {0.f, 0.f};
    const bool full = (nt == SCHUNK);
    if (full) {
#pragma unroll
        for (int grp = 0; grp < SCHUNK / 8; ++grp) {
            f32x2 hb[8];
#pragma unroll
            for (int k = 0; k < 8; ++k)
                hb[k] = *(const f32x2*)(hp + (size_t)(grp * 8 + k) * d);
#pragma unroll
            for (int k = 0; k < 8; ++k) {
                int t = grp * 8 + k;
                float at = sh_a[t], pt = sh_p[t];
                st.x = fmaf(at, st.x, pt * hb[k].x);
                st.y = fmaf(at, st.y, pt * hb[k].y);
            }
        }
    } else {
        for (int t = 0; t < nt; ++t) {
            f32x2 h2 = *(const f32x2*)(hp + (size_t)t * d);
            float at = sh_a[t], pt = sh_p[t];
            st.x = fmaf(at, st.x, pt * h2.x);
            st.y = fmaf(at, st.y, pt * h2.y);
        }
    }

    // ---- publish aggregate (relaxed + waitcnt ordering) ----
    float* ep = aggE + (size_t)g * d + c0;
    agent_store_f(ep + 0, st.x);
    agent_store_f(ep + 1, st.y);
    __syncthreads();            // every wave drains vmcnt before the barrier
    if (tid == 0) {
        agent_store_f(&aggP[g], sh_Pown);
        asm volatile("s_waitcnt vmcnt(0)" ::: "memory");  // aggP before flag
        agent_store_i(&flags[g], 1);
    }

    // ---- decoupled lookback: carry = state at end of chunk g-1 ----
    f32x2 carry = {0.f, 0.f};
    float prodAcc = 1.0f;
    for (int i = g - 1; i >= 0; --i) {
        if (tid == 0) {
            while (agent_load_i(&flags[i]) == 0) __builtin_amdgcn_s_sleep(1);
            sh_Pbr = agent_load_f(&aggP[i]);
        }
        __syncthreads();
        float Pi = sh_Pbr;
        const float* eip = aggE + (size_t)i * d + c0;
        float Ex = agent_load_f(eip + 0);
        float Ey = agent_load_f(eip + 1);
        carry.x = fmaf(prodAcc, Ex, carry.x);
        carry.y = fmaf(prodAcc, Ey, carry.y);
        prodAcc *= Pi;                    // uniform across threads
        __syncthreads();                  // sh_Pbr reused next iteration
        if (prodAcc == 0.0f) break;       // decay underflow / seq reset (~2 steps)
    }

    // ---- pass 2: rescan with carry folded in, scatter f32x2 to out ----
    f32x2 s2 = carry;
    if (full) {
#pragma unroll
        for (int grp = 0; grp < SCHUNK / 8; ++grp) {
            f32x2 hb[8];
#pragma unroll
            for (int k = 0; k < 8; ++k)
                hb[k] = *(const f32x2*)(hp + (size_t)(grp * 8 + k) * d);  // L2/LLC hit
#pragma unroll
            for (int k = 0; k < 8; ++k) {
                int t = grp * 8 + k;
                float at = sh_a[t], pt = sh_p[t];
                s2.x = fmaf(at, s2.x, pt * hb[k].x);
                s2.y = fmaf(at, s2.y, pt * hb[k].y);
                int j0 = max(sh_j[t], 0);
                int j1 = min(sh_j[t + 1], Louter);
                for (int j = j0; j < j1; ++j)
                    __builtin_nontemporal_store(s2, (f32x2*)(out + (size_t)j * d + c0));
            }
        }
    } else {
        for (int t = 0; t < nt; ++t) {
            f32x2 h2 = *(const f32x2*)(hp + (size_t)t * d);
            float at = sh_a[t], pt = sh_p[t];
            s2.x = fmaf(at, s2.x, pt * h2.x);
            s2.y = fmaf(at, s2.y, pt * h2.y);
            int j0 = max(sh_j[t], 0);
            int j1 = min(sh_j[t + 1], Louter);
            for (int j = j0; j < j1; ++j)
                *(f32x2*)(out + (size_t)j * d + c0) = s2;
        }
    }
}

extern "C" void kernel_launch(void* const* d_in, const int* in_sizes, int n_in,
                              void* d_out, int out_size, void* d_ws, size_t ws_size,
                              hipStream_t stream) {
    const float* h     = (const float*)d_in[0];
    const int*   bflat = (const int*)d_in[1];
    const float* psel  = (const float*)d_in[2];
    const int*   seq   = (const int*)d_in[3];
    float* out = (float*)d_out;

    const int L      = in_sizes[2];          // 131072
    const int Louter = in_sizes[1];          // 262144
    const int d      = in_sizes[0] / L;      // 512 (divisible by 2)

    const int NC = (L + SCHUNK - 1) / SCHUNK;   // 2048
    const int nb = (Louter + 1023) / 1024;      // 256 scan blocks

    // workspace layout (256B-aligned slices) — total ~4.6 MB
    char* ws = (char*)d_ws;
    size_t off = 0;
    auto alloc = [&](size_t bytes) -> void* {
        void* p = ws + off;
        off = (off + bytes + 255) & ~(size_t)255;
        return p;
    };
    float* aggE   = (float*)alloc((size_t)NC * d * 4);
    float* aggP   = (float*)alloc((size_t)NC * 4);
    int*   flags  = (int*)alloc((size_t)(NC + 1 + nb) * 4);  // [NC]=ticket, then flags2
    int*   bsum   = (int*)alloc((size_t)nb * 4);
    int*   sidx   = (int*)alloc((size_t)(L + 1) * 4);
    int*   flags2 = flags + NC + 1;
    (void)ws_size;

    clear_kernel<<<(NC + 1 + nb + 255) / 256, 256, 0, stream>>>(flags, NC + 1 + nb);

    sidx_kernel<<<nb, 256, 0, stream>>>(bflat, Louter, bsum, flags2, sidx, L, Louter);

    scan_lookback_kernel<<<NC, d / 2, 0, stream>>>(h, psel, seq, sidx, out,
                                                   aggE, aggP, flags,
                                                   L, d, Louter, NC);
}

// Round 6
// 216.023 us; speedup vs baseline: 1.0665x; 1.0665x over previous
//
#include <hip/hip_runtime.h>
#include <math.h>

#define EPSV 1e-4f
#define SCHUNK 16

// Relaxed agent-scope atomics: point-wise LLC-coherent accesses (sc1), NO
// cache-wide invalidate/writeback (acquire/release would emit buffer_inv /
// buffer_wbl2 on gfx950 since per-XCD L2s are non-coherent -> catastrophic,
// measured round 1: 693 us). Ordering via s_waitcnt vmcnt(0) before flag store.
__device__ __forceinline__ float agent_load_f(const float* p) {
    return __hip_atomic_load(p, __ATOMIC_RELAXED, __HIP_MEMORY_SCOPE_AGENT);
}
__device__ __forceinline__ void agent_store_f(float* p, float v) {
    __hip_atomic_store(p, v, __ATOMIC_RELAXED, __HIP_MEMORY_SCOPE_AGENT);
}
__device__ __forceinline__ int agent_load_i(const int* p) {
    return __hip_atomic_load(p, __ATOMIC_RELAXED, __HIP_MEMORY_SCOPE_AGENT);
}
__device__ __forceinline__ void agent_store_i(int* p, int v) {
    __hip_atomic_store(p, v, __ATOMIC_RELAXED, __HIP_MEMORY_SCOPE_AGENT);
}

// ---------------- clear: flags + ticket ----------------
__global__ void clear_kernel(int* __restrict__ flags, int n) {
    int i = blockIdx.x * blockDim.x + threadIdx.x;
    if (i < n) flags[i] = 0;
}

// ---------------- b_flat scan chain (round-2 proven, verbatim) ----------------
__global__ void scan_sum_kernel(const int* __restrict__ b, int n,
                                int* __restrict__ bsum) {
    __shared__ int red[256];
    int tid = threadIdx.x;
    int base = blockIdx.x * 1024 + tid * 4;
    int s = 0;
#pragma unroll
    for (int k = 0; k < 4; ++k) {
        int j = base + k;
        if (j < n) s += b[j];
    }
    red[tid] = s;
    __syncthreads();
    for (int off = 128; off > 0; off >>= 1) {
        if (tid < off) red[tid] += red[tid + off];
        __syncthreads();
    }
    if (tid == 0) bsum[blockIdx.x] = red[0];
}

__global__ void scan_offsets_kernel(const int* __restrict__ bsum,
                                    int* __restrict__ boff, int nb) {
    __shared__ int sh[1024];
    int i = threadIdx.x;
    int v = (i < nb) ? bsum[i] : 0;
    sh[i] = v;
    __syncthreads();
    for (int off = 1; off < 1024; off <<= 1) {
        int t = sh[i];
        if (i >= off) t += sh[i - off];
        __syncthreads();
        sh[i] = t;
        __syncthreads();
    }
    if (i < nb) boff[i] = sh[i] - v;
}

__global__ void scan_emit_kernel(const int* __restrict__ b, int n,
                                 const int* __restrict__ boff,
                                 int* __restrict__ sidx, int L, int Louter) {
    __shared__ int red[256];
    int tid = threadIdx.x;
    int base = blockIdx.x * 1024 + tid * 4;
    int v[4];
    int s = 0;
#pragma unroll
    for (int k = 0; k < 4; ++k) {
        int j = base + k;
        v[k] = (j < n) ? b[j] : 0;
        s += v[k];
    }
    red[tid] = s;
    __syncthreads();
    for (int off = 1; off < 256; off <<= 1) {
        int t = red[tid];
        if (tid >= off) t += red[tid - off];
        __syncthreads();
        red[tid] = t;
        __syncthreads();
    }
    int cum = red[tid] - s + boff[blockIdx.x];
#pragma unroll
    for (int k = 0; k < 4; ++k) {
        int j = base + k;
        if (j < n) {
            cum += v[k];
            if (v[k] > 0) {
                int t = cum - 1;
                if (t >= 0 && t < L) sidx[t] = j;
            }
        }
    }
    if (base == 0 && blockIdx.x == 0) sidx[L] = Louter;
}

// ---------------- single-pass decoupled-lookback scan + scatter ----------------
// blockDim.x == d (512), ONE channel per thread, scalar loads (round-2 proven
// geometry). SCHUNK=16 so the zero-init local scan z[16] fits in VGPRs
// (statically indexed, fully unrolled) -> h is read EXACTLY ONCE (nontemporal),
// no pass-2 re-read. Lookback depth ~6 (prodAcc = prod of 16 uniforms per chunk
// ~ e^-16; underflows to 0 after ~5-6 chunks; seq resets give exact 0).
// Thread 0 alone spins on predecessor flags (relaxed). Deadlock-free: ticket =>
// predecessors resident; aggregate+flag published before any wait.
__global__ __launch_bounds__(512, 8) void scan_lookback_kernel(
        const float* __restrict__ h,
        const float* __restrict__ psel,
        const int* __restrict__ seq,
        const int* __restrict__ sidx,
        float* __restrict__ out,
        float* __restrict__ aggE,   // [NC][d]
        float* __restrict__ aggP,   // [NC]
        int* __restrict__ flags,    // [NC] flags, flags[NC] = ticket
        int L, int d, int Louter, int NC) {
    __shared__ float sh_a[SCHUNK];
    __shared__ float sh_p[SCHUNK];
    __shared__ float sh_A[SCHUNK];
    __shared__ int   sh_j[SCHUNK + 1];
    __shared__ int   sh_g;
    __shared__ float sh_Pbr;

    const int tid = threadIdx.x;
    if (tid == 0) sh_g = atomicAdd(&flags[NC], 1);  // device-scope ticket
    __syncthreads();
    const int g  = sh_g;
    const int t0 = g * SCHUNK;
    const int nt = min(SCHUNK, L - t0);

    // prologue: per-timestep scalars (fused prep) + scatter ranges into LDS
    if (tid < nt) {
        int t = t0 + tid;
        float p = psel[t];
        p = fminf(fmaxf(p, EPSV), 1.0f - EPSV);
        bool start = (t == 0) || (seq[t] != seq[t - 1]);
        sh_a[tid] = start ? 0.0f : (1.0f - p);   // exp(-dt) == 1-p exactly
        sh_p[tid] = p;                           // b_t = p*h
    }
    if (tid <= nt) sh_j[tid] = sidx[t0 + tid];   // sidx[L] sentinel exists
    __syncthreads();
    if (tid < nt) {                              // A_t = prod_{u<=t} a_u (<=16 mults)
        float prod = 1.0f;
        for (int u = 0; u <= tid; ++u) prod *= sh_a[u];
        sh_A[tid] = prod;
    }
    __syncthreads();

    const int c = tid;
    const float* __restrict__ hp = h + (size_t)t0 * d + c;
    const bool full = (nt == SCHUNK);

    // ---- pass 1: local scan entirely in registers (h read ONCE) ----
    float z[SCHUNK];
    float st = 0.0f;
    if (full) {
        float hb[SCHUNK];
#pragma unroll
        for (int t = 0; t < SCHUNK; ++t)
            hb[t] = __builtin_nontemporal_load(hp + (size_t)t * d);
#pragma unroll
        for (int t = 0; t < SCHUNK; ++t) {
            st = fmaf(sh_a[t], st, sh_p[t] * hb[t]);   // hb[t] dies as z[t] born
            z[t] = st;
        }
    } else {
        for (int t = 0; t < nt; ++t)
            st = fmaf(sh_a[t], st, sh_p[t] * hp[(size_t)t * d]);
    }

    // ---- publish aggregate (relaxed + waitcnt ordering) ----
    agent_store_f(&aggE[(size_t)g * d + c], st);
    __syncthreads();            // every wave drains vmcnt before the barrier
    if (tid == 0) {
        agent_store_f(&aggP[g], sh_A[nt - 1]);         // prod of all a in chunk
        asm volatile("s_waitcnt vmcnt(0)" ::: "memory");  // aggP before flag
        agent_store_i(&flags[g], 1);
    }

    // ---- decoupled lookback: carry = state at end of chunk g-1 ----
    float carry = 0.0f;
    float prodAcc = 1.0f;
    for (int i = g - 1; i >= 0; --i) {
        if (tid == 0) {
            while (agent_load_i(&flags[i]) == 0) __builtin_amdgcn_s_sleep(1);
            sh_Pbr = agent_load_f(&aggP[i]);
        }
        __syncthreads();
        float Pi = sh_Pbr;
        carry = fmaf(prodAcc, agent_load_f(&aggE[(size_t)i * d + c]), carry);
        prodAcc *= Pi;                    // uniform across threads
        __syncthreads();                  // sh_Pbr reused next iteration
        if (prodAcc == 0.0f) break;       // decay underflow / seq reset (~6 steps)
    }

    // ---- pass 2: register-only finalize y_t = A_t*carry + z_t, scatter ----
    if (full) {
#pragma unroll
        for (int t = 0; t < SCHUNK; ++t) {
            float y = fmaf(sh_A[t], carry, z[t]);
            int j0 = max(sh_j[t], 0);
            int j1 = min(sh_j[t + 1], Louter);
            for (int j = j0; j < j1; ++j)
                __builtin_nontemporal_store(y, out + (size_t)j * d + c);
        }
    } else {
        // tail chunk (not hit when L%16==0): rescan with carry folded in
        float s2 = carry;
        for (int t = 0; t < nt; ++t) {
            s2 = fmaf(sh_a[t], s2, sh_p[t] * hp[(size_t)t * d]);
            int j0 = max(sh_j[t], 0);
            int j1 = min(sh_j[t + 1], Louter);
            for (int j = j0; j < j1; ++j)
                out[(size_t)j * d + c] = s2;
        }
    }
}

extern "C" void kernel_launch(void* const* d_in, const int* in_sizes, int n_in,
                              void* d_out, int out_size, void* d_ws, size_t ws_size,
                              hipStream_t stream) {
    const float* h     = (const float*)d_in[0];
    const int*   bflat = (const int*)d_in[1];
    const float* psel  = (const float*)d_in[2];
    const int*   seq   = (const int*)d_in[3];
    float* out = (float*)d_out;

    const int L      = in_sizes[2];          // 131072
    const int Louter = in_sizes[1];          // 262144
    const int d      = in_sizes[0] / L;      // 512

    const int NC = (L + SCHUNK - 1) / SCHUNK;   // 8192
    const int nb = (Louter + 1023) / 1024;      // 256 scan blocks

    // workspace layout (256B-aligned slices) — total ~17.5 MB
    char* ws = (char*)d_ws;
    size_t off = 0;
    auto alloc = [&](size_t bytes) -> void* {
        void* p = ws + off;
        off = (off + bytes + 255) & ~(size_t)255;
        return p;
    };
    float* aggE  = (float*)alloc((size_t)NC * d * 4);
    float* aggP  = (float*)alloc((size_t)NC * 4);
    int*   flags = (int*)alloc((size_t)(NC + 1) * 4);   // +1 = ticket
    int*   bsum  = (int*)alloc((size_t)nb * 4);
    int*   boff  = (int*)alloc((size_t)nb * 4);
    int*   sidx  = (int*)alloc((size_t)(L + 1) * 4);
    (void)ws_size;

    clear_kernel<<<(NC + 1 + 255) / 256, 256, 0, stream>>>(flags, NC + 1);

    scan_sum_kernel<<<nb, 256, 0, stream>>>(bflat, Louter, bsum);
    scan_offsets_kernel<<<1, 1024, 0, stream>>>(bsum, boff, nb);
    scan_emit_kernel<<<nb, 256, 0, stream>>>(bflat, Louter, boff, sidx, L, Louter);

    scan_lookback_kernel<<<NC, d, 0, stream>>>(h, psel, seq, sidx, out,
                                               aggE, aggP, flags,
                                               L, d, Louter, NC);
}

// Round 7
// 180.335 us; speedup vs baseline: 1.2775x; 1.1979x over previous
//
#include <hip/hip_runtime.h>
#include <math.h>

#define EPSV 1e-4f
#define SCHUNK 64

// Relaxed agent-scope atomics: point-wise LLC-coherent accesses (sc1), NO
// cache-wide invalidate/writeback (acquire/release emit buffer_inv/buffer_wbl2
// on gfx950 -> measured 693us disaster in round 1). Ordering done manually
// with s_waitcnt vmcnt(0) before flag stores.
__device__ __forceinline__ float agent_load_f(const float* p) {
    return __hip_atomic_load(p, __ATOMIC_RELAXED, __HIP_MEMORY_SCOPE_AGENT);
}
__device__ __forceinline__ void agent_store_f(float* p, float v) {
    __hip_atomic_store(p, v, __ATOMIC_RELAXED, __HIP_MEMORY_SCOPE_AGENT);
}
__device__ __forceinline__ int agent_load_i(const int* p) {
    return __hip_atomic_load(p, __ATOMIC_RELAXED, __HIP_MEMORY_SCOPE_AGENT);
}
__device__ __forceinline__ void agent_store_i(int* p, int v) {
    __hip_atomic_store(p, v, __ATOMIC_RELAXED, __HIP_MEMORY_SCOPE_AGENT);
}

// ---------------- clear: flags + ticket ----------------
__global__ void clear_kernel(int* __restrict__ flags, int n) {
    int i = blockIdx.x * blockDim.x + threadIdx.x;
    if (i < n) flags[i] = 0;
}

// ---------------- b_flat scan chain (round-2 proven, verbatim) ----------------
__global__ void scan_sum_kernel(const int* __restrict__ b, int n,
                                int* __restrict__ bsum) {
    __shared__ int red[256];
    int tid = threadIdx.x;
    int base = blockIdx.x * 1024 + tid * 4;
    int s = 0;
#pragma unroll
    for (int k = 0; k < 4; ++k) {
        int j = base + k;
        if (j < n) s += b[j];
    }
    red[tid] = s;
    __syncthreads();
    for (int off = 128; off > 0; off >>= 1) {
        if (tid < off) red[tid] += red[tid + off];
        __syncthreads();
    }
    if (tid == 0) bsum[blockIdx.x] = red[0];
}

__global__ void scan_offsets_kernel(const int* __restrict__ bsum,
                                    int* __restrict__ boff, int nb) {
    __shared__ int sh[1024];
    int i = threadIdx.x;
    int v = (i < nb) ? bsum[i] : 0;
    sh[i] = v;
    __syncthreads();
    for (int off = 1; off < 1024; off <<= 1) {
        int t = sh[i];
        if (i >= off) t += sh[i - off];
        __syncthreads();
        sh[i] = t;
        __syncthreads();
    }
    if (i < nb) boff[i] = sh[i] - v;
}

__global__ void scan_emit_kernel(const int* __restrict__ b, int n,
                                 const int* __restrict__ boff,
                                 int* __restrict__ sidx, int L, int Louter) {
    __shared__ int red[256];
    int tid = threadIdx.x;
    int base = blockIdx.x * 1024 + tid * 4;
    int v[4];
    int s = 0;
#pragma unroll
    for (int k = 0; k < 4; ++k) {
        int j = base + k;
        v[k] = (j < n) ? b[j] : 0;
        s += v[k];
    }
    red[tid] = s;
    __syncthreads();
    for (int off = 1; off < 256; off <<= 1) {
        int t = red[tid];
        if (tid >= off) t += red[tid - off];
        __syncthreads();
        red[tid] = t;
        __syncthreads();
    }
    int cum = red[tid] - s + boff[blockIdx.x];
#pragma unroll
    for (int k = 0; k < 4; ++k) {
        int j = base + k;
        if (j < n) {
            cum += v[k];
            if (v[k] > 0) {
                int t = cum - 1;
                if (t >= 0 && t < L) sidx[t] = j;
            }
        }
    }
    if (base == 0 && blockIdx.x == 0) sidx[L] = Louter;
}

// ---------------- single-pass decoupled-lookback scan + scatter ----------------
// blockDim.x == d (512), ONE channel/thread, scalar loads (r2-proven geometry),
// SCHUNK=64 (r2-proven block count NC=2048), but z[64] kept ENTIRELY in VGPRs:
// h is read exactly once (nontemporal), no pass-2 re-read (r2's 268 MB LLC
// traffic gone). __launch_bounds__(512,4) -> 128-VGPR cap; peak live regs
// ~= z[64] + hb[8] + ~20 scalars ~= 95, no spill (r1's failure was a 48-VGPR
// budget). Lookback depth ~2 (P/chunk ~= e^-64 -> prodAcc==0 after 2 steps).
// Thread 0 alone spins (relaxed). Deadlock-free: ticket => predecessors
// resident; aggregate+flag published before any wait.
__global__ __launch_bounds__(512, 4) void scan_lookback_kernel(
        const float* __restrict__ h,
        const float* __restrict__ psel,
        const int* __restrict__ seq,
        const int* __restrict__ sidx,
        float* __restrict__ out,
        float* __restrict__ aggE,   // [NC][d]
        float* __restrict__ aggP,   // [NC]
        int* __restrict__ flags,    // [NC] flags, flags[NC] = ticket
        int L, int d, int Louter, int NC) {
    __shared__ float sh_a[SCHUNK];
    __shared__ float sh_p[SCHUNK];
    __shared__ float sh_A[SCHUNK];   // A_t = prod_{u<=t} a_u
    __shared__ int   sh_j[SCHUNK + 1];
    __shared__ int   sh_g;
    __shared__ float sh_Pbr;

    const int tid = threadIdx.x;
    if (tid == 0) sh_g = atomicAdd(&flags[NC], 1);  // device-scope ticket
    __syncthreads();
    const int g  = sh_g;
    const int t0 = g * SCHUNK;
    const int nt = min(SCHUNK, L - t0);

    // prologue: per-timestep scalars (fused prep) + scatter ranges into LDS
    if (tid < nt) {
        int t = t0 + tid;
        float p = psel[t];
        p = fminf(fmaxf(p, EPSV), 1.0f - EPSV);
        bool start = (t == 0) || (seq[t] != seq[t - 1]);
        sh_a[tid] = start ? 0.0f : (1.0f - p);   // exp(-dt) == 1-p exactly
        sh_p[tid] = p;                           // b_t = p*h
    }
    if (tid <= nt) sh_j[tid] = sidx[t0 + tid];   // sidx[L] sentinel exists
    __syncthreads();

    // wave-0 log-step inclusive prefix-product -> sh_A (6 shfl_up steps)
    if (tid < 64) {
        float v = (tid < nt) ? sh_a[tid] : 1.0f;
#pragma unroll
        for (int off = 1; off < 64; off <<= 1) {
            float w = __shfl_up(v, off);
            if (tid >= off) v *= w;
        }
        sh_A[tid] = v;
    }
    __syncthreads();

    const int c = tid;
    const float* __restrict__ hp = h + (size_t)t0 * d + c;
    const bool full = (nt == SCHUNK);

    // ---- pass 1: local scan fully in registers, h read ONCE (nontemporal) ----
    float z[SCHUNK];
    float st = 0.0f;
    if (full) {
#pragma unroll
        for (int grp = 0; grp < SCHUNK / 8; ++grp) {
            float hb[8];
#pragma unroll
            for (int k = 0; k < 8; ++k)
                hb[k] = __builtin_nontemporal_load(hp + (size_t)(grp * 8 + k) * d);
#pragma unroll
            for (int k = 0; k < 8; ++k) {
                int t = grp * 8 + k;
                st = fmaf(sh_a[t], st, sh_p[t] * hb[k]);
                z[t] = st;                       // static index -> stays in VGPR
            }
        }
    } else {
        for (int t = 0; t < nt; ++t)
            st = fmaf(sh_a[t], st, sh_p[t] * hp[(size_t)t * d]);
    }

    // ---- publish aggregate (relaxed + waitcnt ordering) ----
    agent_store_f(&aggE[(size_t)g * d + c], st);
    __syncthreads();            // drains vmcnt -> all aggE stores complete
    if (tid == 0) {
        agent_store_f(&aggP[g], sh_A[nt - 1]);
        asm volatile("s_waitcnt vmcnt(0)" ::: "memory");  // aggP before flag
        agent_store_i(&flags[g], 1);
    }

    // ---- decoupled lookback: carry = state at end of chunk g-1 ----
    float carry = 0.0f;
    float prodAcc = 1.0f;
    for (int i = g - 1; i >= 0; --i) {
        if (tid == 0) {
            while (agent_load_i(&flags[i]) == 0) __builtin_amdgcn_s_sleep(1);
            sh_Pbr = agent_load_f(&aggP[i]);
        }
        __syncthreads();
        float Pi = sh_Pbr;
        carry = fmaf(prodAcc, agent_load_f(&aggE[(size_t)i * d + c]), carry);
        prodAcc *= Pi;                    // uniform across threads
        __syncthreads();                  // sh_Pbr reused next iteration
        if (prodAcc == 0.0f) break;       // e^-64/chunk -> 0 after ~2 steps
    }

    // ---- pass 2: register-only finalize y_t = A_t*carry + z_t, scatter ----
    if (full) {
#pragma unroll
        for (int t = 0; t < SCHUNK; ++t) {
            float y = fmaf(sh_A[t], carry, z[t]);
            int j0 = max(sh_j[t], 0);
            int j1 = min(sh_j[t + 1], Louter);
            for (int j = j0; j < j1; ++j)
                __builtin_nontemporal_store(y, out + (size_t)j * d + c);
        }
    } else {
        // tail chunk (not hit when L%64==0): rescan with carry folded in
        float s2 = carry;
        for (int t = 0; t < nt; ++t) {
            s2 = fmaf(sh_a[t], s2, sh_p[t] * hp[(size_t)t * d]);
            int j0 = max(sh_j[t], 0);
            int j1 = min(sh_j[t + 1], Louter);
            for (int j = j0; j < j1; ++j)
                out[(size_t)j * d + c] = s2;
        }
    }
}

extern "C" void kernel_launch(void* const* d_in, const int* in_sizes, int n_in,
                              void* d_out, int out_size, void* d_ws, size_t ws_size,
                              hipStream_t stream) {
    const float* h     = (const float*)d_in[0];
    const int*   bflat = (const int*)d_in[1];
    const float* psel  = (const float*)d_in[2];
    const int*   seq   = (const int*)d_in[3];
    float* out = (float*)d_out;

    const int L      = in_sizes[2];          // 131072
    const int Louter = in_sizes[1];          // 262144
    const int d      = in_sizes[0] / L;      // 512

    const int NC = (L + SCHUNK - 1) / SCHUNK;   // 2048
    const int nb = (Louter + 1023) / 1024;      // 256 scan blocks

    // workspace layout (256B-aligned slices) — total ~4.6 MB
    char* ws = (char*)d_ws;
    size_t off = 0;
    auto alloc = [&](size_t bytes) -> void* {
        void* p = ws + off;
        off = (off + bytes + 255) & ~(size_t)255;
        return p;
    };
    float* aggE  = (float*)alloc((size_t)NC * d * 4);
    float* aggP  = (float*)alloc((size_t)NC * 4);
    int*   flags = (int*)alloc((size_t)(NC + 1) * 4);   // +1 = ticket
    int*   bsum  = (int*)alloc((size_t)nb * 4);
    int*   boff  = (int*)alloc((size_t)nb * 4);
    int*   sidx  = (int*)alloc((size_t)(L + 1) * 4);
    (void)ws_size;

    clear_kernel<<<(NC + 1 + 255) / 256, 256, 0, stream>>>(flags, NC + 1);

    scan_sum_kernel<<<nb, 256, 0, stream>>>(bflat, Louter, bsum);
    scan_offsets_kernel<<<1, 1024, 0, stream>>>(bsum, boff, nb);
    scan_emit_kernel<<<nb, 256, 0, stream>>>(bflat, Louter, boff, sidx, L, Louter);

    scan_lookback_kernel<<<NC, d, 0, stream>>>(h, psel, seq, sidx, out,
                                               aggE, aggP, flags,
                                               L, d, Louter, NC);
}